// Round 25
// baseline (381.066 us; speedup 1.0000x reference)
//
#include <hip/hip_runtime.h>
#include <stdint.h>

#define EFFECT_DIM 758
#define ADD_DIM 10
#define EMBED_DIM 768
#define NCOLS 95000
#define NSYN 8
#define NROWS 1024
#define NTN 743              // n-tiles of 128
#define TILE_B 32768         // 256x64 bf16 A tile, fragment-ordered (ws)

typedef __attribute__((ext_vector_type(8))) __bf16 bf16x8;
typedef __attribute__((ext_vector_type(16))) float f32x16;
typedef __attribute__((ext_vector_type(4))) uint32_t u32x4;

// Fragment order: tile = [kk 0..3][grp 0..7][lane 0..63] x 16B.
// frag(kk,grp) = 1KB; lane = (row&31) + (khalf8<<5); 16B = 8 consecutive k.
// R25: fused x high-occupancy. Register budget discovery (R24): waves/SIMD
// = 512 / (archVGPR + AGPR). acc[4][2]=128 AGPR configs are pinned at
// 2 waves/SIMD (22% occ). This config: acc[2][2]=64 AGPR + ~50 arch
// -> 4 waves/SIMD -> 16 waves/CU (launch_bounds(256,4), 32KB LDS).

static __device__ __forceinline__ uint32_t pack2(float a, float b) {
  uint32_t r;
  asm("v_cvt_pk_bf16_f32 %0, %1, %2" : "=v"(r) : "v"(a), "v"(b));
  return r;
}

#define GLOAD16(src, dst)                                                   \
  __builtin_amdgcn_global_load_lds(                                         \
      (const __attribute__((address_space(1))) uint32_t*)(src),             \
      (__attribute__((address_space(3))) uint32_t*)(dst), 16, 0, 0)

// ---------------------------------------------------------------------------
// Kernel 1: VirtualEmbedding -> bf16 A tiles (4 m-tiles x 12 ks), frag order.
// (verified R9-R24; gemm reads 4KB chunks: kk*8192 + (mthalf)*4096)
// ---------------------------------------------------------------------------
__global__ __launch_bounds__(256) void emb_kernel(
    const int* __restrict__ ids, const float* __restrict__ W_emb,
    const float* __restrict__ padding, const int* __restrict__ syn_table,
    const int* __restrict__ syn_mask, char* __restrict__ ws)
{
  const int l = blockIdx.x;
  const int t = threadIdx.x;
  const int id = ids[l];
  int sid[NSYN];
  int msk[NSYN];
#pragma unroll
  for (int k = 0; k < NSYN; ++k) {
    sid[k] = syn_table[id * NSYN + k];
    msk[k] = syn_mask[id * NSYN + k];
  }

  double p[9] = {0, 0, 0, 0, 0, 0, 0, 0, 0};
  for (int d = t; d < EFFECT_DIM; d += 256) {
    p[0] += (double)W_emb[(size_t)id * EFFECT_DIM + d];
#pragma unroll
    for (int k = 0; k < NSYN; ++k)
      p[k + 1] += (double)W_emb[(size_t)sid[k] * EFFECT_DIM + d];
  }

  __shared__ double s_red[9][4];
  const int w = t >> 6;
#pragma unroll
  for (int k = 0; k < 9; ++k) {
    double v = p[k];
#pragma unroll
    for (int off = 32; off > 0; off >>= 1) v += __shfl_down(v, off, 64);
    if ((t & 63) == 0) s_red[k][w] = v;
  }
  __syncthreads();

  const double isum = s_red[0][0] + s_red[0][1] + s_red[0][2] + s_red[0][3];
  float coef[NSYN];
#pragma unroll
  for (int k = 0; k < NSYN; ++k) {
    double ss = s_red[k + 1][0] + s_red[k + 1][1] + s_red[k + 1][2] + s_red[k + 1][3];
    coef[k] = msk[k] ? (float)(isum / ss) : 0.0f;
  }

  const int r = l & 255;
  char* wbase = ws + (size_t)(l >> 8) * (12 * TILE_B);

  for (int j = t; j < 384; j += 256) {
    const int d0 = 2 * j;
    float v0, v1;
    if (d0 < EFFECT_DIM) {
      const float* bp = W_emb + (size_t)id * EFFECT_DIM + d0;
      v0 = bp[0];
      v1 = bp[1];
#pragma unroll
      for (int k = 0; k < NSYN; ++k) {
        const float* sp = W_emb + (size_t)sid[k] * EFFECT_DIM + d0;
        v0 = fmaf(coef[k], sp[0], v0);
        v1 = fmaf(coef[k], sp[1], v1);
      }
    } else {
      v0 = padding[l * ADD_DIM + (d0 - EFFECT_DIM)];
      v1 = padding[l * ADD_DIM + (d0 + 1 - EFFECT_DIM)];
    }
    const int ks   = j >> 5;
    const int jl   = j & 31;
    const int kk   = jl >> 3;
    const int byte = (jl & 7) * 4;
    const int lane = (r & 31) + ((byte >> 4) << 5);
    *(uint32_t*)(wbase + ks * TILE_B + kk * 8192 + (r >> 5) * 1024 +
                 lane * 16 + (byte & 15)) = pack2(v0, v1);
  }
}

// ---------------------------------------------------------------------------
// Kernel 2 (R25): fused GEMM at 4 waves/SIMD. 128x128 tile, BK=32 (24
// steps), 256 thr, 4 waves (2m x 2n), wave 64x64, acc[2][2] = 64 AGPR.
// LDS 32KB static = 2 sets x [A 8K][B 8K], frag-ordered (0 conflicts).
// Per step s (set cs = s&1):
//   AGLD(cs^1, s+1)   // 2 gload_lds (two 4KB kk chunks)
//   BLOAD(br, s+1)    // 16 f32 (2 threads per n, 16 k each)
//   COMPUTE(cs, s)    // 2 phases x {4 ds_read_b128 + 4 MFMA}
//   BSTORE(br, cs^1)  // cvt_pk + 2x ds_write_b128 (data-dep drains vm)
//   lgkmcnt(0); barrier    // TLP (16 waves/CU) hides the drain
// Grid 5944 = 8 mt x 743 nt = 8 XCDs x 743, mt fastest: 8 siblings share
// each 393KB W_rev f32 panel in XCD L2 (64 co-resident blocks = 8 panels).
// ---------------------------------------------------------------------------
__global__ __launch_bounds__(256, 4) void gemm_fused(
    const float* __restrict__ Wrev, const char* __restrict__ Abuf,
    float* __restrict__ out)
{
  __shared__ char lds[32768];  // set s at s*16384: [A 8K][B 8K]
  const int t = threadIdx.x;
  const int l = t & 63;
  const int w = t >> 6;        // 0..3
  const int wm = w >> 1;       // 0..1
  const int wn = w & 1;        // 0..1

  const int wgid = blockIdx.x;            // 5944 = 8 x 743
  const int xcd  = wgid & 7;
  const int work = xcd * NTN + (wgid >> 3);
  const int mt = work & 7;                // 8 m-tiles of 128 rows, fastest
  const int nt = work >> 3;               // 0..742
  const int n0 = nt * 128;

  // A source: ws tile (mt>>1), row-half (mt&1) -> +4096 within each kk chunk
  const char* asrc = Abuf + (size_t)(mt >> 1) * (12 * TILE_B) + (mt & 1) * 4096;

  // B staging: thread owns n = t&127, k-rows kg*16..+15 of the BK=32 step
  const int q  = t & 127;
  const int kg = t >> 7;       // 0..1 == local kk block
  const int gn = n0 + q;
  const bool valid = gn < NCOLS;

  float br[16];

  // step s: A = ws ks (s>>1), kk = 2*(s&1)+c for c in {0,1}
#define AGLD(dst_s, s_)                                                      \
  {                                                                          \
    const char* sa = asrc + ((s_) >> 1) * TILE_B + ((s_) & 1) * 16384;       \
    GLOAD16(sa + t * 16, lds + (dst_s)*16384 + w * 1024);                    \
    GLOAD16(sa + 8192 + t * 16, lds + (dst_s)*16384 + 4096 + w * 1024);      \
  }

#define BLOAD(s_)                                                            \
  {                                                                          \
    const float* p = Wrev + (size_t)((s_)*32 + kg * 16) * NCOLS + gn;        \
    _Pragma("unroll") for (int j = 0; j < 16; ++j)                           \
      br[j] = valid ? p[(size_t)j * NCOLS] : 0.0f;                           \
  }

#define BSTORE(dst_s)                                                        \
  {                                                                          \
    _Pragma("unroll") for (int kh = 0; kh < 2; ++kh) {                       \
      u32x4 u;                                                               \
      _Pragma("unroll") for (int j = 0; j < 4; ++j)                          \
        u[j] = pack2(br[kh * 8 + 2 * j], br[kh * 8 + 2 * j + 1]);            \
      *(u32x4*)(lds + (dst_s)*16384 + 8192 + kg * 4096 + (q >> 5) * 1024 +   \
                ((q & 31) + (kh << 5)) * 16) = u;                            \
    }                                                                        \
  }

#define COMPUTE(cs)                                                          \
  {                                                                          \
    const char* aw = lds + (cs)*16384 + (wm * 2) * 1024 + l * 16;            \
    const char* bw = lds + (cs)*16384 + 8192 + (wn * 2) * 1024 + l * 16;     \
    _Pragma("unroll") for (int p = 0; p < 2; ++p) {                          \
      bf16x8 a[2], b[2];                                                     \
      _Pragma("unroll") for (int mr = 0; mr < 2; ++mr)                       \
        a[mr] = *(const bf16x8*)(aw + p * 4096 + mr * 1024);                 \
      _Pragma("unroll") for (int nr = 0; nr < 2; ++nr)                       \
        b[nr] = *(const bf16x8*)(bw + p * 4096 + nr * 1024);                 \
      __builtin_amdgcn_s_setprio(1);                                         \
      _Pragma("unroll") for (int mr = 0; mr < 2; ++mr)                       \
        _Pragma("unroll") for (int nr = 0; nr < 2; ++nr)                     \
          acc[mr][nr] = __builtin_amdgcn_mfma_f32_32x32x16_bf16(             \
              a[mr], b[nr], acc[mr][nr], 0, 0, 0);                           \
      __builtin_amdgcn_s_setprio(0);                                         \
    }                                                                        \
  }

  // prologue: step 0 -> set 0
  AGLD(0, 0);
  BLOAD(0);
  BSTORE(0);   // data-dep wait on br drains A(0) too (older in queue)
  asm volatile("s_waitcnt vmcnt(0) lgkmcnt(0)" ::: "memory");
  __builtin_amdgcn_s_barrier();

  f32x16 acc[2][2] = {};

  for (int s = 0; s < 24; ++s) {
    const int cs = s & 1;
    const bool pf = (s < 23);

    if (pf) {
      AGLD(cs ^ 1, s + 1);      // oldest in vm queue
      BLOAD(s + 1);             // 16 f32, in flight across compute
    }
    __builtin_amdgcn_sched_barrier(0);
    COMPUTE(cs);
    __builtin_amdgcn_sched_barrier(0);
    if (pf) {
      BSTORE(cs ^ 1);           // compiler waits br -> drains A (older) too
      asm volatile("s_waitcnt vmcnt(0) lgkmcnt(0)" ::: "memory");
      __builtin_amdgcn_sched_barrier(0);
      __builtin_amdgcn_s_barrier();   // next set ready; TLP hides the drain
    }
  }
#undef AGLD
#undef BLOAD
#undef BSTORE
#undef COMPUTE

  // epilogue: C layout col=lane&31, row=(reg&3)+8*(reg>>2)+4*(lane>>5)
  const int lh = l >> 5;
#pragma unroll
  for (int nr = 0; nr < 2; ++nr) {
    const int gc = n0 + wn * 64 + nr * 32 + (l & 31);
    if (gc < NCOLS) {
#pragma unroll
      for (int mr = 0; mr < 2; ++mr)
#pragma unroll
        for (int reg = 0; reg < 16; ++reg) {
          const int row = mt * 128 + wm * 64 + mr * 32 +
                          (reg & 3) + 8 * (reg >> 2) + 4 * lh;
          out[(size_t)row * NCOLS + gc] = acc[mr][nr][reg];
        }
    }
  }
}

extern "C" void kernel_launch(void* const* d_in, const int* in_sizes, int n_in,
                              void* d_out, int out_size, void* d_ws, size_t ws_size,
                              hipStream_t stream) {
  const int*   ids       = (const int*)d_in[0];
  const float* W_emb     = (const float*)d_in[1];
  const float* W_rev     = (const float*)d_in[2];
  const float* padding   = (const float*)d_in[3];
  const int*   syn_table = (const int*)d_in[4];
  const int*   syn_mask  = (const int*)d_in[5];
  float* out = (float*)d_out;
  char*  ws  = (char*)d_ws;

  // A tiles in ws[0, 1.5MB); conv pass deleted
  hipLaunchKernelGGL(emb_kernel, dim3(NROWS), dim3(256), 0, stream,
                     ids, W_emb, padding, syn_table, syn_mask, ws);

  // 5944 blocks: 8 mt x 743 nt = 8 XCDs x 743 (mt fastest on each XCD)
  hipLaunchKernelGGL(gemm_fused, dim3(8 * NTN), dim3(256), 0, stream,
                     W_rev, ws, out);
}

// Round 26
// 327.594 us; speedup vs baseline: 1.1632x; 1.1632x over previous
//
#include <hip/hip_runtime.h>
#include <stdint.h>

#define EFFECT_DIM 758
#define ADD_DIM 10
#define EMBED_DIM 768
#define NCOLS 95000
#define NSYN 8
#define NROWS 1024
#define NT256 372            // ceil(95000/256)
#define TILE_B 32768         // 256x64 bf16 A tile, fragment-ordered

typedef __attribute__((ext_vector_type(8))) __bf16 bf16x8;
typedef __attribute__((ext_vector_type(16))) float f32x16;
typedef __attribute__((ext_vector_type(4))) uint32_t u32x4;

// FINAL (session optimum, measured 326.4us @ R24; band 326-330 across
// R16/R22/R23/R24). Structure: fused single-GEMM (no conv pass), 256x256
// tile, BK=32, 2-deep B register pipeline with counted vmcnt, frag-ordered
// zero-conflict LDS, bijective XCD remap. Refuted alternatives (ledger):
// NT stores (-17%), float4 B (LDS write conflicts), m201 8-barrier phases
// (-20%), 1-wave/SIMD (-22%), high-occ small tile (-17%), LDS-free (-28%).

static __device__ __forceinline__ uint32_t pack2(float a, float b) {
  uint32_t r;
  asm("v_cvt_pk_bf16_f32 %0, %1, %2" : "=v"(r) : "v"(a), "v"(b));
  return r;
}

#define GLOAD16(src, dst)                                                   \
  __builtin_amdgcn_global_load_lds(                                         \
      (const __attribute__((address_space(1))) uint32_t*)(src),             \
      (__attribute__((address_space(3))) uint32_t*)(dst), 16, 0, 0)

// ---------------------------------------------------------------------------
// Kernel 1: VirtualEmbedding -> bf16 A tiles (4 m-tiles x 12 ks), frag order.
// f64 row-sum reductions keep d = i_sum/s_sum bit-accurate vs the f32 ref.
// ---------------------------------------------------------------------------
__global__ __launch_bounds__(256) void emb_kernel(
    const int* __restrict__ ids, const float* __restrict__ W_emb,
    const float* __restrict__ padding, const int* __restrict__ syn_table,
    const int* __restrict__ syn_mask, char* __restrict__ ws)
{
  const int l = blockIdx.x;
  const int t = threadIdx.x;
  const int id = ids[l];
  int sid[NSYN];
  int msk[NSYN];
#pragma unroll
  for (int k = 0; k < NSYN; ++k) {
    sid[k] = syn_table[id * NSYN + k];
    msk[k] = syn_mask[id * NSYN + k];
  }

  double p[9] = {0, 0, 0, 0, 0, 0, 0, 0, 0};
  for (int d = t; d < EFFECT_DIM; d += 256) {
    p[0] += (double)W_emb[(size_t)id * EFFECT_DIM + d];
#pragma unroll
    for (int k = 0; k < NSYN; ++k)
      p[k + 1] += (double)W_emb[(size_t)sid[k] * EFFECT_DIM + d];
  }

  __shared__ double s_red[9][4];
  const int w = t >> 6;
#pragma unroll
  for (int k = 0; k < 9; ++k) {
    double v = p[k];
#pragma unroll
    for (int off = 32; off > 0; off >>= 1) v += __shfl_down(v, off, 64);
    if ((t & 63) == 0) s_red[k][w] = v;
  }
  __syncthreads();

  const double isum = s_red[0][0] + s_red[0][1] + s_red[0][2] + s_red[0][3];
  float coef[NSYN];
#pragma unroll
  for (int k = 0; k < NSYN; ++k) {
    double ss = s_red[k + 1][0] + s_red[k + 1][1] + s_red[k + 1][2] + s_red[k + 1][3];
    coef[k] = msk[k] ? (float)(isum / ss) : 0.0f;
  }

  const int r = l & 255;
  char* wbase = ws + (size_t)(l >> 8) * (12 * TILE_B);

  for (int j = t; j < 384; j += 256) {
    const int d0 = 2 * j;
    float v0, v1;
    if (d0 < EFFECT_DIM) {
      const float* bp = W_emb + (size_t)id * EFFECT_DIM + d0;
      v0 = bp[0];
      v1 = bp[1];
#pragma unroll
      for (int k = 0; k < NSYN; ++k) {
        const float* sp = W_emb + (size_t)sid[k] * EFFECT_DIM + d0;
        v0 = fmaf(coef[k], sp[0], v0);
        v1 = fmaf(coef[k], sp[1], v1);
      }
    } else {
      v0 = padding[l * ADD_DIM + (d0 - EFFECT_DIM)];
      v1 = padding[l * ADD_DIM + (d0 + 1 - EFFECT_DIM)];
    }
    const int ks   = j >> 5;
    const int jl   = j & 31;
    const int kk   = jl >> 3;
    const int byte = (jl & 7) * 4;
    const int lane = (r & 31) + ((byte >> 4) << 5);
    *(uint32_t*)(wbase + ks * TILE_B + kk * 8192 + (r >> 5) * 1024 +
                 lane * 16 + (byte & 15)) = pack2(v0, v1);
  }
}

// ---------------------------------------------------------------------------
// Kernel 2: fused GEMM. 256x256 tile, BK=32 (24 steps), 512 thr, 8 waves
// (2m x 4n), wave 128x64, acc[4][2]. LDS 64KB static = 2 sets x [A 16K][B 16K]
// frag-ordered (0 bank conflicts). Per K-step s (set cs = s&1):
//   AGLD(cs^1, s+1)          // 2 gload_lds (16KB half-tile), OLDEST in queue
//   BLOAD(brNext, s+2)       // 16 f32 loads, stay in flight 2 steps
//   2 x {6 ds_read_b128 + 8 MFMA (setprio)}
//   BSTORE(brCur = B(s+1))   // loaded a FULL step ago -> retired, no stall
//   lgkmcnt(0); vmcnt(16)    // A(s+1) confirmed (older), B(s+2) in flight
//   s_barrier
// A source: step s reads bytes [(s&1)*16384, +16K) of ws tile (s>>1).
// T1 remap 1488 = 8 x 186 (bijective): 4 mt-siblings share each W_rev f32
// panel on one XCD's L2 (FETCH ~190MB vs 574MB unswizzled, measured).
// ---------------------------------------------------------------------------
__global__ __launch_bounds__(512, 2) void gemm_fused(
    const float* __restrict__ Wrev, const char* __restrict__ Abuf,
    float* __restrict__ out)
{
  __shared__ char lds[65536];  // set s at s*32768: [A 16K][B 16K]
  const int t = threadIdx.x;
  const int l = t & 63;
  const int w = t >> 6;
  const int wm = w >> 2;       // 0..1
  const int wn = w & 3;        // 0..3

  const int wgid = blockIdx.x;            // 1488 = 8 x 186
  const int xcd  = wgid & 7;
  const int work = xcd * 186 + (wgid >> 3);
  const int mt = work & 3;
  const int nt = work >> 2;
  const int n0 = nt * 256;

  const char* asrc = Abuf + (size_t)mt * (12 * TILE_B);

  // B staging role: thread owns col sn (0..255), k-rows kg*16..+15 of BK=32
  const int sn = t & 255;
  const int kg = t >> 8;       // 0..1
  const int gn = n0 + sn;
  const bool valid = gn < NCOLS;

  float br0[16], br1[16];

  // step s: A half-tile = ws tile (s>>1), byte half (s&1)*16384
#define AGLD(dst_s, s_)                                                      \
  {                                                                          \
    const char* sa = asrc + ((s_) >> 1) * TILE_B + ((s_) & 1) * 16384;       \
    GLOAD16(sa + t * 16, lds + (dst_s)*32768 + w * 1024);                    \
    GLOAD16(sa + 8192 + t * 16, lds + (dst_s)*32768 + 8192 + w * 1024);      \
  }

#define BLOAD(br, s_)                                                        \
  {                                                                          \
    const float* p = Wrev + (size_t)((s_)*32 + kg * 16) * NCOLS + gn;        \
    _Pragma("unroll") for (int j = 0; j < 16; ++j)                           \
      br[j] = valid ? p[(size_t)j * NCOLS] : 0.0f;                           \
  }

#define BSTORE(br, dst_s)                                                    \
  {                                                                          \
    _Pragma("unroll") for (int kh = 0; kh < 2; ++kh) {                       \
      u32x4 u;                                                               \
      _Pragma("unroll") for (int j = 0; j < 4; ++j)                          \
        u[j] = pack2(br[kh * 8 + 2 * j], br[kh * 8 + 2 * j + 1]);            \
      *(u32x4*)(lds + (dst_s)*32768 + 16384 + kg * 8192 + (sn >> 5) * 1024 + \
                ((sn & 31) + (kh << 5)) * 16) = u;                           \
    }                                                                        \
  }

#define COMPUTE(cs)                                                          \
  {                                                                          \
    const char* aw = lds + (cs)*32768 + (wm * 4) * 1024 + l * 16;            \
    const char* bw = lds + (cs)*32768 + 16384 + (wn * 2) * 1024 + l * 16;    \
    _Pragma("unroll") for (int p = 0; p < 2; ++p) {                          \
      bf16x8 a[4], b[2];                                                     \
      _Pragma("unroll") for (int mr = 0; mr < 4; ++mr)                       \
        a[mr] = *(const bf16x8*)(aw + p * 8192 + mr * 1024);                 \
      _Pragma("unroll") for (int nr = 0; nr < 2; ++nr)                       \
        b[nr] = *(const bf16x8*)(bw + p * 8192 + nr * 1024);                 \
      __builtin_amdgcn_s_setprio(1);                                         \
      _Pragma("unroll") for (int mr = 0; mr < 4; ++mr)                       \
        _Pragma("unroll") for (int nr = 0; nr < 2; ++nr)                     \
          acc[mr][nr] = __builtin_amdgcn_mfma_f32_32x32x16_bf16(             \
              a[mr], b[nr], acc[mr][nr], 0, 0, 0);                           \
      __builtin_amdgcn_s_setprio(0);                                         \
    }                                                                        \
  }

  // one pipelined step: compute set cs / step SS; prep set cs^1
#define STEP(cs, SS, brCur, brNext)                                          \
  {                                                                          \
    if ((SS) + 1 < 24) AGLD((cs) ^ 1, (SS) + 1);       /* oldest in queue */ \
    if ((SS) + 2 < 24) BLOAD(brNext, (SS) + 2);                              \
    __builtin_amdgcn_sched_barrier(0);                                       \
    COMPUTE(cs);                                                             \
    __builtin_amdgcn_sched_barrier(0);                                       \
    if ((SS) + 1 < 24) {                                                     \
      BSTORE(brCur, (cs) ^ 1);         /* brCur loaded a full step ago */    \
      asm volatile("s_waitcnt lgkmcnt(0)" ::: "memory");                     \
      if ((SS) + 2 < 24) asm volatile("s_waitcnt vmcnt(16)" ::: "memory");   \
      else               asm volatile("s_waitcnt vmcnt(0)" ::: "memory");    \
      __builtin_amdgcn_sched_barrier(0);                                     \
      __builtin_amdgcn_s_barrier();                                          \
    }                                                                        \
  }

  // prologue: step 0 -> set 0; preload B(1) into br0
  AGLD(0, 0);
  BLOAD(br0, 0);
  BSTORE(br0, 0);   // compiler waits br0 (drains A(0) too — older)
  BLOAD(br0, 1);
  asm volatile("s_waitcnt lgkmcnt(0)" ::: "memory");
  __builtin_amdgcn_sched_barrier(0);
  __builtin_amdgcn_s_barrier();

  f32x16 acc[4][2] = {};

#pragma unroll
  for (int Si = 0; Si < 12; ++Si) {
    STEP(0, 2 * Si,     br0, br1);
    STEP(1, 2 * Si + 1, br1, br0);
  }
#undef STEP
#undef COMPUTE
#undef AGLD
#undef BLOAD
#undef BSTORE

  // epilogue: C layout col=lane&31, row=(reg&3)+8*(reg>>2)+4*(lane>>5)
  const int lh = l >> 5;
#pragma unroll
  for (int nr = 0; nr < 2; ++nr) {
    const int gc = n0 + wn * 64 + nr * 32 + (l & 31);
    if (gc < NCOLS) {
#pragma unroll
      for (int mr = 0; mr < 4; ++mr)
#pragma unroll
        for (int reg = 0; reg < 16; ++reg) {
          const int row = mt * 256 + wm * 128 + mr * 32 +
                          (reg & 3) + 8 * (reg >> 2) + 4 * lh;
          out[(size_t)row * NCOLS + gc] = acc[mr][nr][reg];
        }
    }
  }
}

extern "C" void kernel_launch(void* const* d_in, const int* in_sizes, int n_in,
                              void* d_out, int out_size, void* d_ws, size_t ws_size,
                              hipStream_t stream) {
  const int*   ids       = (const int*)d_in[0];
  const float* W_emb     = (const float*)d_in[1];
  const float* W_rev     = (const float*)d_in[2];
  const float* padding   = (const float*)d_in[3];
  const int*   syn_table = (const int*)d_in[4];
  const int*   syn_mask  = (const int*)d_in[5];
  float* out = (float*)d_out;
  char*  ws  = (char*)d_ws;

  // A tiles in ws[0, 1.5MB); conv pass deleted
  hipLaunchKernelGGL(emb_kernel, dim3(NROWS), dim3(256), 0, stream,
                     ids, W_emb, padding, syn_table, syn_mask, ws);

  // 1488 blocks: 4 m-tiles x 372 n-tiles = 8 XCDs x 186 (bijective)
  hipLaunchKernelGGL(gemm_fused, dim3(4 * NT256), dim3(512), 0, stream,
                     W_rev, ws, out);
}